// Round 8
// baseline (728.358 us; speedup 1.0000x reference)
//
#include <hip/hip_runtime.h>
#include <hip/hip_bf16.h>

#define S_LEN 4096
#define HID 768
#define NHEAD 12
#define HL 64
#define NBLK 768u

typedef __attribute__((ext_vector_type(8))) short short8;
typedef __attribute__((ext_vector_type(4))) float f32x4;
using bf16 = __hip_bfloat16;

__device__ __forceinline__ void gl2lds16(const void* g, void* l) {
  __builtin_amdgcn_global_load_lds((__attribute__((address_space(1))) void*)(g),
                                   (__attribute__((address_space(3))) void*)(l),
                                   16, 0, 0);
}

__device__ __forceinline__ f32x4 mfma_bf16(short8 a, short8 b, f32x4 c) {
  return __builtin_amdgcn_mfma_f32_16x16x32_bf16(a, b, c, 0, 0, 0);
}

// lgkmcnt-only barrier (flash K-loop): K/V register prefetch stays in flight
#define BAR() asm volatile("s_waitcnt lgkmcnt(0)\n\ts_barrier" ::: "memory")

// device-scope grid barrier. Safe because all 768 blocks are co-resident:
// launch_bounds(256,3) caps VGPR<=168 (3 waves/SIMD), LDS 33.8KB (4 blocks/CU
// cap), 12 waves/CU <= 32  =>  3 blocks/CU x 256 CU = 768. __threadfence is an
// agent-scope fence (L2 writeback/invalidate) covering cross-XCD visibility.
__device__ __forceinline__ void gridbar(unsigned* cnt, int idx) {
  __syncthreads();          // all waves drained (incl. vmcnt: compiler semantics)
  __threadfence();          // release: flush this XCD's L2
  if (threadIdx.x == 0) {
    atomicAdd(&cnt[idx], 1u);
    while (__hip_atomic_load(&cnt[idx], __ATOMIC_RELAXED,
                             __HIP_MEMORY_SCOPE_AGENT) < NBLK)
      __builtin_amdgcn_s_sleep(8);
  }
  __syncthreads();
  __threadfence();          // acquire: invalidate stale lines before reading
}

// ============================ the whole op, one kernel ========================
// P0 cvt fp32->bf16 | P1 QKV gemm (128x96, 768 tiles; V written transposed)
// | P2 flash v5 | P3 fc gemm (64x64, 768 tiles). 3 grid barriers.
__global__ __launch_bounds__(256, 3) void mha_mega(
    const float* __restrict__ x, const float* __restrict__ wq,
    const float* __restrict__ wk, const float* __restrict__ wv,
    const float* __restrict__ wfc, bf16* __restrict__ xb,
    bf16* __restrict__ wqb, bf16* __restrict__ wkb, bf16* __restrict__ wvb,
    bf16* __restrict__ wfcb, bf16* __restrict__ Qb, bf16* __restrict__ Kb,
    bf16* __restrict__ Vtb, bf16* __restrict__ Ob, float* __restrict__ out,
    unsigned* __restrict__ cnt) {
  __shared__ __align__(16) char SMEM[33792];  // union: P1 14.3K/26.1K, P2 33.8K, P3 8K
  const int b = blockIdx.x;
  const int t = threadIdx.x, lane = t & 63, w = t >> 6;
  const int q4 = lane >> 4, c16 = lane & 15;
  const float c1 = 0.125f * 1.44269504088896340736f;  // softmax scale * log2(e)

  // ---------------- P0: convert x + 4 weights to bf16 (7 float4/thread) ------
  {
    const long NX4 = (long)S_LEN * HID / 4;  // 786432
    const long NW4 = (long)HID * HID / 4;    // 147456
#pragma unroll
    for (int i = 0; i < 7; ++i) {
      long g = (long)i * 196608 + (long)b * 256 + t;
      const float4* src;
      ushort4* dst;
      long off;
      if (g < NX4) {
        src = (const float4*)x; dst = (ushort4*)xb; off = g;
      } else {
        long j = g - NX4;
        int zz = (int)(j / NW4);
        off = j - (long)zz * NW4;
        src = (const float4*)(zz == 0 ? wq : zz == 1 ? wk : zz == 2 ? wv : wfc);
        dst = (ushort4*)(zz == 0 ? wqb : zz == 1 ? wkb : zz == 2 ? wvb : wfcb);
      }
      float4 v = src[off];
      bf16 h0 = __float2bfloat16(v.x), h1 = __float2bfloat16(v.y);
      bf16 h2 = __float2bfloat16(v.z), h3 = __float2bfloat16(v.w);
      ushort4 o;
      o.x = *(unsigned short*)&h0; o.y = *(unsigned short*)&h1;
      o.z = *(unsigned short*)&h2; o.w = *(unsigned short*)&h3;
      dst[off] = o;
    }
  }
  gridbar(cnt, 0);

  // ---------------- P1: QKV gemm, tile 128x96 -> exactly 768 tiles ----------
  // z = b>>8 picks Q/K/V; bn in 8 (96-col tiles), bm in 32 (128-row tiles).
  // z==2 (V): epilogue transposes the C-tile via LDS and writes Vt[e][s].
  {
    bf16* As = (bf16*)SMEM;                    // [128*32]
    bf16* Bs = (bf16*)(SMEM + 128 * 32 * 2);   // [96*32]
    const int z = b >> 8, r8 = b & 255, bn = r8 & 7, bm = r8 >> 3;
    const bf16* A = xb + (long)bm * 128 * HID;
    const bf16* Bw = (z == 0 ? wqb : z == 1 ? wkb : wvb) + (long)bn * 96 * HID;
    const int wm = w >> 1, wn = w & 1;
    const int srow = lane >> 2, scol = (lane & 3) * 8;
    f32x4 acc[4][3] = {};
    for (int k0 = 0; k0 < HID; k0 += 32) {
      gl2lds16(A + (long)(w * 16 + srow) * HID + k0 + scol, &As[w * 16 * 32]);
      gl2lds16(A + (long)(64 + w * 16 + srow) * HID + k0 + scol,
               &As[(64 + w * 16) * 32]);
      gl2lds16(Bw + (long)(w * 16 + srow) * HID + k0 + scol, &Bs[w * 16 * 32]);
      if (w < 2)
        gl2lds16(Bw + (long)(64 + w * 16 + srow) * HID + k0 + scol,
                 &Bs[(64 + w * 16) * 32]);
      __syncthreads();
      short8 af[4], bfv[3];
#pragma unroll
      for (int i = 0; i < 4; ++i)
        af[i] = *(const short8*)&As[(wm * 64 + i * 16 + c16) * 32 + q4 * 8];
#pragma unroll
      for (int j = 0; j < 3; ++j)
        bfv[j] = *(const short8*)&Bs[(wn * 48 + j * 16 + c16) * 32 + q4 * 8];
#pragma unroll
      for (int i = 0; i < 4; ++i)
#pragma unroll
        for (int j = 0; j < 3; ++j)
          acc[i][j] = mfma_bf16(af[i], bfv[j], acc[i][j]);
      __syncthreads();
    }
    if (z < 2) {
      bf16* C = (z == 0) ? Qb : Kb;
      const float sc = (z == 0) ? c1 : 1.0f;
#pragma unroll
      for (int i = 0; i < 4; ++i)
#pragma unroll
        for (int j = 0; j < 3; ++j)
#pragma unroll
          for (int r = 0; r < 4; ++r) {
            long row = (long)bm * 128 + wm * 64 + i * 16 + q4 * 4 + r;
            int col = bn * 96 + wn * 48 + j * 16 + c16;
            C[row * HID + col] = __float2bfloat16(sc * acc[i][j][r]);
          }
    } else {
      // V: transpose C-tile (128 s x 96 e) -> Vt[e][s] via LDS [96][136]
      bf16* Lt = (bf16*)SMEM;
#pragma unroll
      for (int i = 0; i < 4; ++i)
#pragma unroll
        for (int j = 0; j < 3; ++j) {
          bf16 b0 = __float2bfloat16(acc[i][j][0]);
          bf16 b1 = __float2bfloat16(acc[i][j][1]);
          bf16 b2 = __float2bfloat16(acc[i][j][2]);
          bf16 b3 = __float2bfloat16(acc[i][j][3]);
          short4 pk;
          pk.x = *(short*)&b0; pk.y = *(short*)&b1;
          pk.z = *(short*)&b2; pk.w = *(short*)&b3;
          *(short4*)&Lt[(wn * 48 + j * 16 + c16) * 136 + wm * 64 + i * 16 +
                        q4 * 4] = pk;
        }
      __syncthreads();
#pragma unroll
      for (int p = 0; p < 6; ++p) {
        int e = p * 16 + (t >> 4);
        int s = (t & 15) * 8;
        short8 vv = *(const short8*)&Lt[e * 136 + s];
        *(short8*)&Vtb[(long)(bn * 96 + e) * S_LEN + bm * 128 + s] = vv;
      }
    }
  }
  gridbar(cnt, 1);

  // ---------------- P2: flash attention v5 (BKV=128, 1 lgkm barrier/iter) ----
  {
    bf16* Ps0 = (bf16*)SMEM;          // [64*128] x2 buffers = 32 KB
    float* Lred = (float*)(SMEM + 32768);  // [4][64]
    const int qt = b & 63, h = b >> 6;
    const int s0 = qt * 64;

    short8 qf[2][4];
    {
      const bf16* Qp = Qb + (long)(s0 + c16) * HID + h * HL + q4 * 8;
#pragma unroll
      for (int j = 0; j < 4; ++j)
#pragma unroll
        for (int ks = 0; ks < 2; ++ks)
          qf[ks][j] = *(const short8*)(Qp + (long)j * 16 * HID + ks * 32);
    }
    const bf16* kp = Kb + (long)(w * 32 + c16) * HID + h * HL + q4 * 8;
    const bf16* vp = Vtb + (long)(h * HL + w * 16 + c16) * S_LEN + q4 * 8;

    float l_part[4] = {0.f, 0.f, 0.f, 0.f};
    f32x4 o_acc[4] = {};
    short8 kf[2][2], vf[4];
#pragma unroll
    for (int rr = 0; rr < 2; ++rr)
#pragma unroll
      for (int ks = 0; ks < 2; ++ks)
        kf[rr][ks] = *(const short8*)(kp + (long)rr * 16 * HID + ks * 32);
#pragma unroll
    for (int kc = 0; kc < 4; ++kc) vf[kc] = *(const short8*)(vp + kc * 32);

    for (int kt = 0; kt < S_LEN / 128; ++kt) {
      bf16* Pb = Ps0 + (kt & 1) * 64 * 128;
      f32x4 sacc[2][4] = {};
#pragma unroll
      for (int rr = 0; rr < 2; ++rr)
#pragma unroll
        for (int ks = 0; ks < 2; ++ks)
#pragma unroll
          for (int j = 0; j < 4; ++j)
            sacc[rr][j] = mfma_bf16(kf[rr][ks], qf[ks][j], sacc[rr][j]);

      const bf16* kpn = (kt == S_LEN / 128 - 1) ? kp : kp + 128 * HID;
#pragma unroll
      for (int rr = 0; rr < 2; ++rr)
#pragma unroll
        for (int ks = 0; ks < 2; ++ks)
          kf[rr][ks] = *(const short8*)(kpn + (long)rr * 16 * HID + ks * 32);
      kp = kpn;

#pragma unroll
      for (int rr = 0; rr < 2; ++rr) {
        const int wch = (w * 4 + rr * 2 + (q4 >> 1));
#pragma unroll
        for (int j = 0; j < 4; ++j) {
          float p0 = __builtin_amdgcn_exp2f(sacc[rr][j][0]);
          float p1 = __builtin_amdgcn_exp2f(sacc[rr][j][1]);
          float p2 = __builtin_amdgcn_exp2f(sacc[rr][j][2]);
          float p3 = __builtin_amdgcn_exp2f(sacc[rr][j][3]);
          l_part[j] += (p0 + p1) + (p2 + p3);
          __hip_bfloat162 a01 = __float22bfloat162_rn(float2{p0, p1});
          __hip_bfloat162 a23 = __float22bfloat162_rn(float2{p2, p3});
          int2 pk;
          pk.x = *(int*)&a01;
          pk.y = *(int*)&a23;
          *(int2*)&Pb[(j * 16 + c16) * 128 + (wch ^ c16) * 8 + (q4 & 1) * 4] = pk;
        }
      }
      BAR();  // P visible; K/V prefetch vmcnt NOT drained

#pragma unroll
      for (int kc = 0; kc < 4; ++kc) {
#pragma unroll
        for (int j = 0; j < 4; ++j) {
          short8 pf = *(const short8*)&Pb[(j * 16 + c16) * 128 +
                                          ((kc * 4 + q4) ^ c16) * 8];
          o_acc[j] = mfma_bf16(vf[kc], pf, o_acc[j]);
        }
      }
      const bf16* vpn = (kt == S_LEN / 128 - 1) ? vp : vp + 128;
#pragma unroll
      for (int kc = 0; kc < 4; ++kc) vf[kc] = *(const short8*)(vpn + kc * 32);
      vp = vpn;
    }

#pragma unroll
    for (int j = 0; j < 4; ++j) {
      float s = l_part[j];
      s += __shfl_xor(s, 16, 64);
      s += __shfl_xor(s, 32, 64);
      Lred[w * 64 + j * 16 + c16] = s;
    }
    __syncthreads();
#pragma unroll
    for (int j = 0; j < 4; ++j) {
      int q = j * 16 + c16;
      float lt = Lred[0 * 64 + q] + Lred[1 * 64 + q] + Lred[2 * 64 + q] +
                 Lred[3 * 64 + q];
      float rl = 1.0f / lt;
      float v0 = o_acc[j][0] * rl, v1 = o_acc[j][1] * rl;
      float v2 = o_acc[j][2] * rl, v3 = o_acc[j][3] * rl;
      bf16 b0 = __float2bfloat16(v0), b1 = __float2bfloat16(v1);
      bf16 b2 = __float2bfloat16(v2), b3 = __float2bfloat16(v3);
      short4 pk;
      pk.x = *(short*)&b0; pk.y = *(short*)&b1;
      pk.z = *(short*)&b2; pk.w = *(short*)&b3;
      *(short4*)&Ob[(long)(s0 + q) * HID + h * HL + w * 16 + q4 * 4] = pk;
    }
  }
  gridbar(cnt, 2);

  // ---------------- P3: fc gemm, 64x64 tiles -> exactly 768 ----------------
  {
    bf16* As = (bf16*)SMEM;                   // [64*32]
    bf16* Bs = (bf16*)(SMEM + 64 * 32 * 2);   // [64*32]
    const int bn = b % 12, bm = b / 12;
    const bf16* A = Ob + (long)bm * 64 * HID;
    const bf16* Bw = wfcb + (long)bn * 64 * HID;
    const int wm = w >> 1, wn = w & 1;
    const int srow = lane >> 2, scol = (lane & 3) * 8;
    f32x4 acc[2][2] = {};
    for (int k0 = 0; k0 < HID; k0 += 32) {
      gl2lds16(A + (long)(w * 16 + srow) * HID + k0 + scol, &As[w * 16 * 32]);
      gl2lds16(Bw + (long)(w * 16 + srow) * HID + k0 + scol, &Bs[w * 16 * 32]);
      __syncthreads();
      short8 af[2], bfv[2];
#pragma unroll
      for (int i = 0; i < 2; ++i)
        af[i] = *(const short8*)&As[(wm * 32 + i * 16 + c16) * 32 + q4 * 8];
#pragma unroll
      for (int j = 0; j < 2; ++j)
        bfv[j] = *(const short8*)&Bs[(wn * 32 + j * 16 + c16) * 32 + q4 * 8];
#pragma unroll
      for (int i = 0; i < 2; ++i)
#pragma unroll
        for (int j = 0; j < 2; ++j)
          acc[i][j] = mfma_bf16(af[i], bfv[j], acc[i][j]);
      __syncthreads();
    }
#pragma unroll
    for (int i = 0; i < 2; ++i)
#pragma unroll
      for (int j = 0; j < 2; ++j)
#pragma unroll
        for (int r = 0; r < 4; ++r) {
          long row = (long)bm * 64 + wm * 32 + i * 16 + q4 * 4 + r;
          int col = bn * 64 + wn * 32 + j * 16 + c16;
          out[row * HID + col] = acc[i][j][r];
        }
  }
}

extern "C" void kernel_launch(void* const* d_in, const int* in_sizes, int n_in,
                              void* d_out, int out_size, void* d_ws, size_t ws_size,
                              hipStream_t stream) {
  const float* x = (const float*)d_in[0];
  const float* wq = (const float*)d_in[1];
  const float* wk = (const float*)d_in[2];
  const float* wv = (const float*)d_in[3];
  const float* wfc = (const float*)d_in[4];
  float* out = (float*)d_out;

  const long NBIG = (long)S_LEN * HID * sizeof(bf16);  // 6.29 MB
  const long NWB = (long)HID * HID * sizeof(bf16);     // 1.18 MB
  char* p = (char*)d_ws;
  unsigned* cnt = (unsigned*)p; p += 256;  // grid-barrier counters
  bf16* xb = (bf16*)p;   p += NBIG;
  bf16* wqb = (bf16*)p;  p += NWB;
  bf16* wkb = (bf16*)p;  p += NWB;
  bf16* wvb = (bf16*)p;  p += NWB;
  bf16* wfcb = (bf16*)p; p += NWB;
  bf16* Qb = (bf16*)p;   p += NBIG;
  bf16* Kb = (bf16*)p;   p += NBIG;
  bf16* Vtb = (bf16*)p;  p += NBIG;
  bf16* Ob = (bf16*)p;   p += NBIG;

  // zero the barrier counters (harness poisons d_ws to 0xAA before each launch)
  hipMemsetAsync(cnt, 0, 256, stream);
  mha_mega<<<NBLK, 256, 0, stream>>>(x, wq, wk, wv, wfc, xb, wqb, wkb, wvb, wfcb,
                                     Qb, Kb, Vtb, Ob, out, cnt);
}